// Round 1
// baseline (47.479 us; speedup 1.0000x reference)
//
#include <hip/hip_runtime.h>
#include <hip/hip_bf16.h>
#include <stdint.h>

// Problem constants
#define B_ROWS 16384
#define F_DIM  512
#define K_OUT  1000
#define K_PAD  1024

// GEMM tile
#define BM 128
#define BN 128
#define BK 64

typedef __attribute__((ext_vector_type(4))) float f32x4;
typedef __attribute__((ext_vector_type(8))) short short8;
typedef unsigned short u16;
typedef unsigned int   u32;

// Workspace layout (bytes)
#define OFF_DB   0                               // 16384*512*2 = 16777216
#define OFF_WB   16777216                        // 1024*512*2  = 1048576
#define OFF_DSQ  (16777216 + 1048576)            // 16384*4     = 65536
#define OFF_WSQ  (16777216 + 1048576 + 65536)    // 1024*4      = 4096

__device__ __forceinline__ u16 f2bf(float f) {
  union { float f; u32 u; } v; v.f = f;
  u32 u = v.u;
  u32 r = (u + 0x7fffu + ((u >> 16) & 1u)) >> 16;   // RNE
  return (u16)r;
}

// ---- prep: cast D -> bf16, compute row sum-of-squares (one wave per row) ----
__global__ void prep_D(const float* __restrict__ D, u16* __restrict__ Db,
                       float* __restrict__ dsq) {
  int w    = threadIdx.x >> 6;
  int lane = threadIdx.x & 63;
  int row  = blockIdx.x * 4 + w;
  const float* src = D + (size_t)row * F_DIM + lane * 8;
  float4 v0 = *(const float4*)src;
  float4 v1 = *(const float4*)(src + 4);
  float s = v0.x*v0.x + v0.y*v0.y + v0.z*v0.z + v0.w*v0.w
          + v1.x*v1.x + v1.y*v1.y + v1.z*v1.z + v1.w*v1.w;
#pragma unroll
  for (int off = 32; off >= 1; off >>= 1) s += __shfl_xor(s, off);
  if (lane == 0) dsq[row] = s;
  uint4 p;
  p.x = (u32)f2bf(v0.x) | ((u32)f2bf(v0.y) << 16);
  p.y = (u32)f2bf(v0.z) | ((u32)f2bf(v0.w) << 16);
  p.z = (u32)f2bf(v1.x) | ((u32)f2bf(v1.y) << 16);
  p.w = (u32)f2bf(v1.z) | ((u32)f2bf(v1.w) << 16);
  *(uint4*)(Db + (size_t)row * F_DIM + lane * 8) = p;
}

// ---- prep: cast W -> bf16 padded to K_PAD rows, compute row sum-of-squares ----
__global__ void prep_W(const float* __restrict__ W, u16* __restrict__ Wb,
                       float* __restrict__ wsq) {
  int w    = threadIdx.x >> 6;
  int lane = threadIdx.x & 63;
  int row  = blockIdx.x * 4 + w;
  uint4 p; p.x = p.y = p.z = p.w = 0u;
  float s = 0.f;
  if (row < K_OUT) {
    const float* src = W + (size_t)row * F_DIM + lane * 8;
    float4 v0 = *(const float4*)src;
    float4 v1 = *(const float4*)(src + 4);
    s = v0.x*v0.x + v0.y*v0.y + v0.z*v0.z + v0.w*v0.w
      + v1.x*v1.x + v1.y*v1.y + v1.z*v1.z + v1.w*v1.w;
    p.x = (u32)f2bf(v0.x) | ((u32)f2bf(v0.y) << 16);
    p.y = (u32)f2bf(v0.z) | ((u32)f2bf(v0.w) << 16);
    p.z = (u32)f2bf(v1.x) | ((u32)f2bf(v1.y) << 16);
    p.w = (u32)f2bf(v1.z) | ((u32)f2bf(v1.w) << 16);
  }
#pragma unroll
  for (int off = 32; off >= 1; off >>= 1) s += __shfl_xor(s, off);
  if (lane == 0) wsq[row] = s;
  *(uint4*)(Wb + (size_t)row * F_DIM + lane * 8) = p;
}

// ---- async global -> LDS, 16B per lane (dest is wave-uniform base + lane*16) ----
__device__ __forceinline__ void gload_lds16(const void* g, void* l) {
  __builtin_amdgcn_global_load_lds(
      (const __attribute__((address_space(1))) void*)g,
      (__attribute__((address_space(3))) void*)l,
      16, 0, 0);
}

// ---- main GEMM + fused epilogue ----
// out[m][n] = gamma[n] * (2*cross[m][n] - dsq[m] - wsq[n]), n < K_OUT
__global__ __launch_bounds__(256) void gemm_eps(
    const u16* __restrict__ A,   // [B_ROWS][F_DIM] bf16
    const u16* __restrict__ Bw,  // [K_PAD][F_DIM]  bf16 (padded rows are 0)
    const float* __restrict__ dsq,
    const float* __restrict__ wsq,
    const float* __restrict__ gamma,
    float* __restrict__ out) {
  __shared__ u16 sA[BM * BK];
  __shared__ u16 sB[BN * BK];
  char* sAc = (char*)sA;
  char* sBc = (char*)sB;

  int tid  = threadIdx.x;
  int w    = tid >> 6;
  int lane = tid & 63;
  int lr   = lane & 15;    // fragment row (A) / col (B)
  int lk   = lane >> 4;    // k-chunk 0..3
  int wm   = w >> 1;       // wave 2x2 grid over the 128x128 tile
  int wn   = w & 1;

  // XCD-aware swizzle (nwg = 1024, divisible by 8 -> bijective)
  int bid = blockIdx.x;
  int cpx = gridDim.x >> 3;
  int wg  = (bid & 7) * cpx + (bid >> 3);
  int mt  = wg >> 3;       // 8 N-tiles
  int nt  = wg & 7;
  int m0  = mt * BM;
  int n0  = nt * BN;

  const u16* Ag = A  + (size_t)m0 * F_DIM;
  const u16* Bg = Bw + (size_t)n0 * F_DIM;

  f32x4 acc[4][4];
#pragma unroll
  for (int i = 0; i < 4; ++i)
#pragma unroll
    for (int j = 0; j < 4; ++j)
      acc[i][j] = (f32x4){0.f, 0.f, 0.f, 0.f};

  // staging decomposition: LDS linear byte L = i*4096 + w*1024 + lane*16
  // -> tile row r = i*32 + w*8 + lane/8, 16B-slot s = lane&7.
  // pre-swizzled SOURCE: slot s of row r receives global slot (s ^ (r&7)).
  int rs  = w * 8 + (lane >> 3);
  int s8  = lane & 7;

  for (int kt = 0; kt < F_DIM / BK; ++kt) {
    int kbase = kt * BK;
#pragma unroll
    for (int i = 0; i < 4; ++i) {
      int r  = i * 32 + rs;
      int sc = s8 ^ (r & 7);
      gload_lds16(Ag + (size_t)r * F_DIM + kbase + sc * 8, sAc + i * 4096 + w * 1024);
      gload_lds16(Bg + (size_t)r * F_DIM + kbase + sc * 8, sBc + i * 4096 + w * 1024);
    }
    __syncthreads();   // compiler drains vmcnt(0) before s_barrier -> LDS ready
#pragma unroll
    for (int t = 0; t < 2; ++t) {
      short8 af[4], bfr[4];
#pragma unroll
      for (int mi = 0; mi < 4; ++mi) {
        int r = wm * 64 + mi * 16 + lr;
        int s = (t * 4 + lk) ^ (r & 7);
        af[mi] = *(const short8*)(sAc + r * 128 + (s << 4));
      }
#pragma unroll
      for (int ni = 0; ni < 4; ++ni) {
        int r = wn * 64 + ni * 16 + lr;
        int s = (t * 4 + lk) ^ (r & 7);
        bfr[ni] = *(const short8*)(sBc + r * 128 + (s << 4));
      }
#pragma unroll
      for (int mi = 0; mi < 4; ++mi)
#pragma unroll
        for (int ni = 0; ni < 4; ++ni)
          acc[mi][ni] = __builtin_amdgcn_mfma_f32_16x16x32_bf16(
              af[mi], bfr[ni], acc[mi][ni], 0, 0, 0);
    }
    __syncthreads();
  }

  // fused epilogue: C/D layout col = lane&15, row = (lane>>4)*4 + reg
  float dl[4][4];
#pragma unroll
  for (int mi = 0; mi < 4; ++mi) {
    int r0 = m0 + wm * 64 + mi * 16 + lk * 4;
#pragma unroll
    for (int j = 0; j < 4; ++j) dl[mi][j] = dsq[r0 + j];
  }
#pragma unroll
  for (int ni = 0; ni < 4; ++ni) {
    int col = n0 + wn * 64 + ni * 16 + lr;
    if (col < K_OUT) {
      float g  = gamma[col];
      float wq = wsq[col];
#pragma unroll
      for (int mi = 0; mi < 4; ++mi) {
        int r0 = m0 + wm * 64 + mi * 16 + lk * 4;
#pragma unroll
        for (int j = 0; j < 4; ++j) {
          out[(size_t)(r0 + j) * K_OUT + col] =
              g * (2.0f * acc[mi][ni][j] - dl[mi][j] - wq);
        }
      }
    }
  }
}

extern "C" void kernel_launch(void* const* d_in, const int* in_sizes, int n_in,
                              void* d_out, int out_size, void* d_ws, size_t ws_size,
                              hipStream_t stream) {
  const float* D     = (const float*)d_in[0];
  const float* W     = (const float*)d_in[1];
  const float* gamma = (const float*)d_in[2];
  float* out = (float*)d_out;
  char*  ws  = (char*)d_ws;

  u16*   Db  = (u16*)(ws + OFF_DB);
  u16*   Wb  = (u16*)(ws + OFF_WB);
  float* dsq = (float*)(ws + OFF_DSQ);
  float* wsq = (float*)(ws + OFF_WSQ);

  // casts + norms
  prep_D<<<B_ROWS / 4, 256, 0, stream>>>(D, Db, dsq);
  prep_W<<<K_PAD / 4, 256, 0, stream>>>(W, Wb, wsq);

  // GEMM + fused epilogue: grid = (16384/128) * (1024/128) = 1024 blocks
  gemm_eps<<<(B_ROWS / BM) * (K_PAD / BN), 256, 0, stream>>>(
      Db, Wb, dsq, wsq, gamma, out);
}

// Round 2
// 44.011 us; speedup vs baseline: 1.0788x; 1.0788x over previous
//
#include <hip/hip_runtime.h>
#include <hip/hip_bf16.h>
#include <stdint.h>

// Problem constants
#define B_ROWS 16384
#define F_DIM  512
#define K_OUT  1000
#define K_PAD  1024

// GEMM tile (256x256, BK=64, 8 waves)
#define BM 256
#define BN 256
#define BK 64

typedef __attribute__((ext_vector_type(4))) float f32x4;
typedef __attribute__((ext_vector_type(8))) short short8;
typedef unsigned short u16;
typedef unsigned int   u32;

// Workspace layout (bytes)
#define OFF_DB   0                               // 16384*512*2 = 16777216
#define OFF_WB   16777216                        // 1024*512*2  = 1048576
#define OFF_DSQ  (16777216 + 1048576)            // 16384*4     = 65536
#define OFF_WSQ  (16777216 + 1048576 + 65536)    // 1024*4      = 4096

__device__ __forceinline__ u16 f2bf(float f) {
  union { float f; u32 u; } v; v.f = f;
  u32 u = v.u;
  u32 r = (u + 0x7fffu + ((u >> 16) & 1u)) >> 16;   // RNE
  return (u16)r;
}

// ---- prep: cast D -> bf16, compute row sum-of-squares (one wave per row) ----
__global__ void prep_D(const float* __restrict__ D, u16* __restrict__ Db,
                       float* __restrict__ dsq) {
  int w    = threadIdx.x >> 6;
  int lane = threadIdx.x & 63;
  int row  = blockIdx.x * 4 + w;
  const float* src = D + (size_t)row * F_DIM + lane * 8;
  float4 v0 = *(const float4*)src;
  float4 v1 = *(const float4*)(src + 4);
  float s = v0.x*v0.x + v0.y*v0.y + v0.z*v0.z + v0.w*v0.w
          + v1.x*v1.x + v1.y*v1.y + v1.z*v1.z + v1.w*v1.w;
#pragma unroll
  for (int off = 32; off >= 1; off >>= 1) s += __shfl_xor(s, off);
  if (lane == 0) dsq[row] = s;
  uint4 p;
  p.x = (u32)f2bf(v0.x) | ((u32)f2bf(v0.y) << 16);
  p.y = (u32)f2bf(v0.z) | ((u32)f2bf(v0.w) << 16);
  p.z = (u32)f2bf(v1.x) | ((u32)f2bf(v1.y) << 16);
  p.w = (u32)f2bf(v1.z) | ((u32)f2bf(v1.w) << 16);
  *(uint4*)(Db + (size_t)row * F_DIM + lane * 8) = p;
}

// ---- prep: cast W -> bf16 padded to K_PAD rows, compute row sum-of-squares ----
__global__ void prep_W(const float* __restrict__ W, u16* __restrict__ Wb,
                       float* __restrict__ wsq) {
  int w    = threadIdx.x >> 6;
  int lane = threadIdx.x & 63;
  int row  = blockIdx.x * 4 + w;
  uint4 p; p.x = p.y = p.z = p.w = 0u;
  float s = 0.f;
  if (row < K_OUT) {
    const float* src = W + (size_t)row * F_DIM + lane * 8;
    float4 v0 = *(const float4*)src;
    float4 v1 = *(const float4*)(src + 4);
    s = v0.x*v0.x + v0.y*v0.y + v0.z*v0.z + v0.w*v0.w
      + v1.x*v1.x + v1.y*v1.y + v1.z*v1.z + v1.w*v1.w;
    p.x = (u32)f2bf(v0.x) | ((u32)f2bf(v0.y) << 16);
    p.y = (u32)f2bf(v0.z) | ((u32)f2bf(v0.w) << 16);
    p.z = (u32)f2bf(v1.x) | ((u32)f2bf(v1.y) << 16);
    p.w = (u32)f2bf(v1.z) | ((u32)f2bf(v1.w) << 16);
  }
#pragma unroll
  for (int off = 32; off >= 1; off >>= 1) s += __shfl_xor(s, off);
  if (lane == 0) wsq[row] = s;
  *(uint4*)(Wb + (size_t)row * F_DIM + lane * 8) = p;
}

// ---- async global -> LDS, 16B per lane (dest is wave-uniform base + lane*16) ----
__device__ __forceinline__ void gload_lds16(const void* g, void* l) {
  __builtin_amdgcn_global_load_lds(
      (const __attribute__((address_space(1))) void*)g,
      (__attribute__((address_space(3))) void*)l,
      16, 0, 0);
}

// ---- main GEMM + fused epilogue: 256x256 tile, 8 waves, phase-split K-step ----
// out[m][n] = gamma[n] * (2*cross[m][n] - dsq[m] - wsq[n]), n < K_OUT

// Per-phase fragment reads. LDS tile layout: [256 rows][64 cols] bf16, row = 128B
// = 8 slots of 16B; slot stored at (slot ^ (row&7)) -- matches pre-swizzled
// global source used in staging (both-sides involution, rule #21).
#define READ_A(QM)                                                             \
  _Pragma("unroll") for (int mi2 = 0; mi2 < 4; ++mi2)                          \
  _Pragma("unroll") for (int kk = 0; kk < 2; ++kk) {                           \
    int r = wm * 128 + ((QM) * 4 + mi2) * 16 + lr;                             \
    a[mi2][kk] = *(const short8*)(sAc + r * 128 +                              \
                                  ((((kk << 2) + lk4) ^ (r & 7)) << 4));       \
  }

#define READ_B(QN)                                                             \
  _Pragma("unroll") for (int ni2 = 0; ni2 < 2; ++ni2)                          \
  _Pragma("unroll") for (int kk = 0; kk < 2; ++kk) {                           \
    int r = wn * 64 + ((QN) * 2 + ni2) * 16 + lr;                              \
    b[ni2][kk] = *(const short8*)(sBc + r * 128 +                              \
                                  ((((kk << 2) + lk4) ^ (r & 7)) << 4));       \
  }

// Stage one 16KB half-slot (rows Q*64..Q*64+63) of the NEXT K-tile for A and B.
#define STAGE(Q)                                                               \
  if (t < 7) {                                                                 \
    int r  = (Q) * 64 + srow;                                                  \
    int sc = s8 ^ (r & 7);                                                     \
    gload_lds16(Ag + (size_t)r * F_DIM + kbn + sc * 8,                         \
                sAn + (Q) * 8192 + w * 1024);                                  \
    gload_lds16(Bg + (size_t)r * F_DIM + kbn + sc * 8,                         \
                sBn + (Q) * 8192 + w * 1024);                                  \
  }

// One phase: raw barrier -> lgkm drain -> setprio(1) -> 16 MFMA -> raw barrier.
#define MFMA16(QM, QN)                                                         \
  __builtin_amdgcn_s_barrier();                                                \
  asm volatile("s_waitcnt lgkmcnt(0)" ::: "memory");                           \
  __builtin_amdgcn_sched_barrier(0);                                           \
  __builtin_amdgcn_s_setprio(1);                                               \
  _Pragma("unroll") for (int mi2 = 0; mi2 < 4; ++mi2)                          \
  _Pragma("unroll") for (int ni2 = 0; ni2 < 2; ++ni2)                          \
  _Pragma("unroll") for (int kk = 0; kk < 2; ++kk)                             \
    acc[(QM)*4 + mi2][(QN)*2 + ni2] =                                          \
        __builtin_amdgcn_mfma_f32_16x16x32_bf16(                               \
            a[mi2][kk], b[ni2][kk], acc[(QM)*4 + mi2][(QN)*2 + ni2], 0, 0, 0); \
  __builtin_amdgcn_s_setprio(0);                                               \
  __builtin_amdgcn_s_barrier();

__global__ __launch_bounds__(512, 2) void gemm_eps(
    const u16* __restrict__ A,   // [B_ROWS][F_DIM] bf16
    const u16* __restrict__ Bw,  // [K_PAD][F_DIM]  bf16 (padded rows are 0)
    const float* __restrict__ dsq,
    const float* __restrict__ wsq,
    const float* __restrict__ gamma,
    float* __restrict__ out) {
  __shared__ __align__(16) char lds[131072];   // 2 x (A 32KB + B 32KB)

  const int tid  = threadIdx.x;
  const int w    = tid >> 6;     // wave 0..7
  const int lane = tid & 63;
  const int lr   = lane & 15;
  const int lk4  = lane >> 4;
  const int wm   = w >> 2;       // 2 M-waves
  const int wn   = w & 3;        // 4 N-waves

  // XCD-aware swizzle (grid=256, 256%8==0 -> bijective)
  const int bid = blockIdx.x;
  const int wg  = (bid & 7) * 32 + (bid >> 3);
  const int mt  = wg >> 2;       // 64 M-tiles
  const int nt  = wg & 3;        // 4 N-tiles
  const int m0  = mt * BM;
  const int n0  = nt * BN;

  const u16* Ag = A  + (size_t)m0 * F_DIM;
  const u16* Bg = Bw + (size_t)n0 * F_DIM;

  const int srow = w * 8 + (lane >> 3);   // staging row within 64-row slot
  const int s8   = lane & 7;              // staging 16B slot

  f32x4 acc[8][4];
#pragma unroll
  for (int i = 0; i < 8; ++i)
#pragma unroll
    for (int j = 0; j < 4; ++j) acc[i][j] = (f32x4){0.f, 0.f, 0.f, 0.f};

  // prologue: stage K-tile 0 into buf0
#pragma unroll
  for (int q = 0; q < 4; ++q) {
    int r  = q * 64 + srow;
    int sc = s8 ^ (r & 7);
    gload_lds16(Ag + (size_t)r * F_DIM + sc * 8, lds + q * 8192 + w * 1024);
    gload_lds16(Bg + (size_t)r * F_DIM + sc * 8, lds + 32768 + q * 8192 + w * 1024);
  }
  __syncthreads();   // drains own vmcnt(0) -> tile 0 resident

#pragma unroll 2
  for (int t = 0; t < 8; ++t) {
    char* sAc = lds + (t & 1) * 65536;
    char* sBc = sAc + 32768;
    char* sAn = lds + ((t + 1) & 1) * 65536;
    char* sBn = sAn + 32768;
    const int kbn = (t + 1) * 64;
    short8 a[4][2], b[2][2];

    // 4 phases, Gray-code quadrant order: reuse A across N-halves, B across
    // M-halves -> 28 ds_read_b128 per K-tile (near-minimal LDS traffic).
    READ_A(0) READ_B(0) STAGE(0) MFMA16(0, 0)
    READ_B(1)           STAGE(1) MFMA16(0, 1)
    READ_A(1)           STAGE(2) MFMA16(1, 1)
    READ_B(0)           STAGE(3) MFMA16(1, 0)

    __syncthreads();   // boundary: drains the 8 prefetch loads + barrier
  }

  // ---- fused epilogue via LDS transpose (coalesced 128B row stores) ----
  float g_[4], wq_[4];
#pragma unroll
  for (int ni = 0; ni < 4; ++ni) {
    int col = n0 + wn * 64 + ni * 16 + lr;
    g_[ni]  = (col < K_OUT) ? gamma[col] : 0.f;
    wq_[ni] = (col < K_OUT) ? wsq[col]   : 0.f;
  }
  float* ch = (float*)lds;       // chunk buffer [64][260] f32 (pad 260: 16B-aligned
  const int rl = tid >> 3;       // rows, 2-way-max LDS bank aliasing)
  const int cb = (tid & 7) << 2;
#pragma unroll
  for (int c = 0; c < 4; ++c) {
    __syncthreads();   // previous chunk fully read (and K-loop LDS quiesced)
    if (wm == (c >> 1)) {
#pragma unroll
      for (int mi2 = 0; mi2 < 4; ++mi2) {
        const int mi    = ((c & 1) << 2) + mi2;
        const int row_l = mi2 * 16 + lk4 * 4;
        const int grow  = m0 + c * 64 + row_l;
#pragma unroll
        for (int j = 0; j < 4; ++j) {
          float dq = dsq[grow + j];
#pragma unroll
          for (int ni = 0; ni < 4; ++ni) {
            ch[(row_l + j) * 260 + wn * 64 + ni * 16 + lr] =
                g_[ni] * (2.f * acc[mi][ni][j] - dq - wq_[ni]);
          }
        }
      }
    }
    __syncthreads();   // chunk visible to all waves
#pragma unroll
    for (int s = 0; s < 8; ++s) {
      int col = cb + s * 32;
      if (n0 + col < K_OUT) {
        float4 v = *(const float4*)&ch[rl * 260 + col];
        *(float4*)&out[(size_t)(m0 + c * 64 + rl) * K_OUT + n0 + col] = v;
      }
    }
  }
}

extern "C" void kernel_launch(void* const* d_in, const int* in_sizes, int n_in,
                              void* d_out, int out_size, void* d_ws, size_t ws_size,
                              hipStream_t stream) {
  const float* D     = (const float*)d_in[0];
  const float* W     = (const float*)d_in[1];
  const float* gamma = (const float*)d_in[2];
  float* out = (float*)d_out;
  char*  ws  = (char*)d_ws;

  u16*   Db  = (u16*)(ws + OFF_DB);
  u16*   Wb  = (u16*)(ws + OFF_WB);
  float* dsq = (float*)(ws + OFF_DSQ);
  float* wsq = (float*)(ws + OFF_WSQ);

  prep_D<<<B_ROWS / 4, 256, 0, stream>>>(D, Db, dsq);
  prep_W<<<K_PAD / 4, 256, 0, stream>>>(W, Wb, wsq);

  // grid = (16384/256) * (1024/256) = 64*4 = 256 blocks, 1 per CU
  gemm_eps<<<(B_ROWS / BM) * (K_PAD / BN), 512, 0, stream>>>(
      Db, Wb, dsq, wsq, gamma, out);
}

// Round 3
// 42.210 us; speedup vs baseline: 1.1248x; 1.0427x over previous
//
#include <hip/hip_runtime.h>
#include <hip/hip_bf16.h>
#include <stdint.h>

// Problem constants
#define B_ROWS 16384
#define F_DIM  512
#define K_OUT  1000
#define K_PAD  1024

// GEMM tile (256x256, BK=64, 8 waves)
#define BM 256
#define BN 256
#define BK 64

typedef __attribute__((ext_vector_type(4))) float f32x4;
typedef __attribute__((ext_vector_type(8))) short short8;
typedef unsigned short u16;
typedef unsigned int   u32;

// Workspace layout (bytes)
#define OFF_DB   0                               // 16384*512*2 = 16777216
#define OFF_WB   16777216                        // 1024*512*2  = 1048576
#define OFF_DSQ  (16777216 + 1048576)            // 16384*4     = 65536
#define OFF_WSQ  (16777216 + 1048576 + 65536)    // 1024*4      = 4096

__device__ __forceinline__ u16 f2bf(float f) {
  union { float f; u32 u; } v; v.f = f;
  u32 u = v.u;
  u32 r = (u + 0x7fffu + ((u >> 16) & 1u)) >> 16;   // RNE
  return (u16)r;
}

// ---- merged prep: cast D,W -> bf16 (+pad W), row sums of squares ----
__global__ void prep(const float* __restrict__ D, const float* __restrict__ W,
                     u16* __restrict__ Db, u16* __restrict__ Wb,
                     float* __restrict__ dsq, float* __restrict__ wsq) {
  int w    = threadIdx.x >> 6;
  int lane = threadIdx.x & 63;
  if (blockIdx.x < B_ROWS / 4) {
    int row = blockIdx.x * 4 + w;
    const float* src = D + (size_t)row * F_DIM + lane * 8;
    float4 v0 = *(const float4*)src;
    float4 v1 = *(const float4*)(src + 4);
    float s = v0.x*v0.x + v0.y*v0.y + v0.z*v0.z + v0.w*v0.w
            + v1.x*v1.x + v1.y*v1.y + v1.z*v1.z + v1.w*v1.w;
#pragma unroll
    for (int off = 32; off >= 1; off >>= 1) s += __shfl_xor(s, off);
    if (lane == 0) dsq[row] = s;
    uint4 p;
    p.x = (u32)f2bf(v0.x) | ((u32)f2bf(v0.y) << 16);
    p.y = (u32)f2bf(v0.z) | ((u32)f2bf(v0.w) << 16);
    p.z = (u32)f2bf(v1.x) | ((u32)f2bf(v1.y) << 16);
    p.w = (u32)f2bf(v1.z) | ((u32)f2bf(v1.w) << 16);
    *(uint4*)(Db + (size_t)row * F_DIM + lane * 8) = p;
  } else {
    int row = (blockIdx.x - B_ROWS / 4) * 4 + w;
    uint4 p; p.x = p.y = p.z = p.w = 0u;
    float s = 0.f;
    if (row < K_OUT) {
      const float* src = W + (size_t)row * F_DIM + lane * 8;
      float4 v0 = *(const float4*)src;
      float4 v1 = *(const float4*)(src + 4);
      s = v0.x*v0.x + v0.y*v0.y + v0.z*v0.z + v0.w*v0.w
        + v1.x*v1.x + v1.y*v1.y + v1.z*v1.z + v1.w*v1.w;
      p.x = (u32)f2bf(v0.x) | ((u32)f2bf(v0.y) << 16);
      p.y = (u32)f2bf(v0.z) | ((u32)f2bf(v0.w) << 16);
      p.z = (u32)f2bf(v1.x) | ((u32)f2bf(v1.y) << 16);
      p.w = (u32)f2bf(v1.z) | ((u32)f2bf(v1.w) << 16);
    }
#pragma unroll
    for (int off = 32; off >= 1; off >>= 1) s += __shfl_xor(s, off);
    if (lane == 0) wsq[row] = s;
    *(uint4*)(Wb + (size_t)row * F_DIM + lane * 8) = p;
  }
}

// ---- async global -> LDS, 16B per lane (dest is wave-uniform base + lane*16) ----
__device__ __forceinline__ void gload_lds16(const void* g, void* l) {
  __builtin_amdgcn_global_load_lds(
      (const __attribute__((address_space(1))) void*)g,
      (__attribute__((address_space(3))) void*)l,
      16, 0, 0);
}

// ---- main GEMM + fused epilogue: 256x256 tile, 8 waves, counted-vmcnt pipeline ----
// out[m][n] = gamma[n] * (2*cross[m][n] - dsq[m] - wsq[n]), n < K_OUT
//
// LDS tile: [256 rows][64 cols] bf16, row = 128B = 8 slots of 16B; slot stored at
// (slot ^ (row&7)), achieved by pre-swizzling the per-lane GLOBAL source address
// (both-sides involution, rule #21). Reads use the same XOR.
//
// Staging is chunked to match phase consumption (Gray-code phases (0,0)(0,1)(1,1)(1,0)):
//   chunk A0 = A rows {0-63, 128-191}   (what READ_A(0) touches across wm=0/1)
//   chunk A1 = A rows {64-127, 192-255}
//   chunk B0 = B rows with bit5==0      (what READ_B(0) touches across wn=0..3)
//   chunk B1 = B rows with bit5==1
// Per-thread ledger (2 loads per chunk, issue order A0,B0,B1,A1 per tile):
//   enter tile: 8 outstanding; P1 +2 -> vmcnt(6) completes A0,B0; P2 +2 ->
//   vmcnt(6) completes B1; P3 +2 -> vmcnt(6) completes A1; P4 +2, no wait.
//   Never below 6 in flight; no vmcnt(0) anywhere in the main loop (T4).

#define READ_A(QM)                                                             \
  _Pragma("unroll") for (int mi2 = 0; mi2 < 4; ++mi2)                          \
  _Pragma("unroll") for (int kk = 0; kk < 2; ++kk) {                           \
    int r = wm * 128 + ((QM) * 4 + mi2) * 16 + lr;                             \
    a[mi2][kk] = *(const short8*)(sAc + r * 128 +                              \
                                  ((((kk << 2) + lk4) ^ (r & 7)) << 4));       \
  }

#define READ_B(QN)                                                             \
  _Pragma("unroll") for (int ni2 = 0; ni2 < 2; ++ni2)                          \
  _Pragma("unroll") for (int kk = 0; kk < 2; ++kk) {                           \
    int r = wn * 64 + ((QN) * 2 + ni2) * 16 + lr;                              \
    b[ni2][kk] = *(const short8*)(sBc + r * 128 +                              \
                                  ((((kk << 2) + lk4) ^ (r & 7)) << 4));       \
  }

// Stage chunk A_h of the next K-tile: rows h*64 + {0-63} and h*64 + {128-191}.
#define STAGE_A(h)                                                             \
  _Pragma("unroll") for (int j = 0; j < 2; ++j) {                              \
    int r  = (h) * 64 + j * 128 + srow;                                        \
    int sc = s8 ^ (r & 7);                                                     \
    gload_lds16(Ag + (size_t)r * F_DIM + kbn + sc * 8,                         \
                sAn + (h) * 8192 + j * 16384 + w * 1024);                      \
  }

// Stage chunk B_q of the next K-tile: the 128 rows with bit5==q.
#define STAGE_B(q)                                                             \
  _Pragma("unroll") for (int j = 0; j < 2; ++j) {                              \
    int g  = j * 8 + w;                                                        \
    int rb = ((g >> 2) << 6) + (q) * 32 + ((g & 3) << 3);                      \
    int r  = rb + (lane >> 3);                                                 \
    int sc = s8 ^ (r & 7);                                                     \
    gload_lds16(Bg + (size_t)r * F_DIM + kbn + sc * 8, sBn + rb * 128);        \
  }

#define MFMA_Q(QM, QN)                                                         \
  asm volatile("s_waitcnt lgkmcnt(0)" ::: "memory");                           \
  __builtin_amdgcn_sched_barrier(0);                                           \
  __builtin_amdgcn_s_setprio(1);                                               \
  _Pragma("unroll") for (int mi2 = 0; mi2 < 4; ++mi2)                          \
  _Pragma("unroll") for (int ni2 = 0; ni2 < 2; ++ni2)                          \
  _Pragma("unroll") for (int kk = 0; kk < 2; ++kk)                             \
    acc[(QM)*4 + mi2][(QN)*2 + ni2] =                                          \
        __builtin_amdgcn_mfma_f32_16x16x32_bf16(                               \
            a[mi2][kk], b[ni2][kk], acc[(QM)*4 + mi2][(QN)*2 + ni2], 0, 0, 0); \
  __builtin_amdgcn_s_setprio(0);                                               \
  __builtin_amdgcn_s_barrier();

#define VM6  asm volatile("s_waitcnt vmcnt(6)" ::: "memory")
#define BAR  __builtin_amdgcn_s_barrier()

__global__ __launch_bounds__(512, 2) void gemm_eps(
    const u16* __restrict__ A,   // [B_ROWS][F_DIM] bf16
    const u16* __restrict__ Bw,  // [K_PAD][F_DIM]  bf16 (padded rows are 0)
    const float* __restrict__ dsq,
    const float* __restrict__ wsq,
    const float* __restrict__ gamma,
    float* __restrict__ out) {
  __shared__ __align__(16) char lds[131072];   // 2 x (A 32KB + B 32KB)

  const int tid  = threadIdx.x;
  const int w    = tid >> 6;     // wave 0..7
  const int lane = tid & 63;
  const int lr   = lane & 15;
  const int lk4  = lane >> 4;
  const int wm   = w >> 2;       // 2 M-waves
  const int wn   = w & 3;        // 4 N-waves

  // XCD-aware swizzle (grid=256, 256%8==0 -> bijective)
  const int bid = blockIdx.x;
  const int wg  = (bid & 7) * 32 + (bid >> 3);
  const int mt  = wg >> 2;       // 64 M-tiles
  const int nt  = wg & 3;        // 4 N-tiles
  const int m0  = mt * BM;
  const int n0  = nt * BN;

  const u16* Ag = A  + (size_t)m0 * F_DIM;
  const u16* Bg = Bw + (size_t)n0 * F_DIM;

  const int srow = w * 8 + (lane >> 3);   // staging row within a 64-row group
  const int s8   = lane & 7;              // staging 16B slot

  f32x4 acc[8][4];
#pragma unroll
  for (int i = 0; i < 8; ++i)
#pragma unroll
    for (int j = 0; j < 4; ++j) acc[i][j] = (f32x4){0.f, 0.f, 0.f, 0.f};

  // prologue: stage all 4 chunks of K-tile 0 into buf0, in ledger order.
  {
    char* sAn = lds;
    char* sBn = lds + 32768;
    const int kbn = 0;
    STAGE_A(0) STAGE_B(0) STAGE_B(1) STAGE_A(1)
  }
  // no wait here: P1 of tile 0 does vmcnt(6) which completes A0,B0.

#pragma unroll 2
  for (int t = 0; t < 8; ++t) {
    char* sAc = lds + (t & 1) * 65536;
    char* sBc = sAc + 32768;
    char* sAn = lds + ((t + 1) & 1) * 65536;
    char* sBn = sAn + 32768;
    const int kbn = ((t + 1) & 7) * BK;  // tile 8 wraps to k=0: harmless, drained later
    short8 a[4][2], b[2][2];

    // P1 (QM=0,QN=0): needs A0,B0 of this tile
    STAGE_A(0) VM6; BAR;
    READ_A(0) READ_B(0)
    MFMA_Q(0, 0)
    // P2 (0,1): needs B1
    STAGE_B(0) VM6; BAR;
    READ_B(1)
    MFMA_Q(0, 1)
    // P3 (1,1): needs A1
    STAGE_B(1) VM6; BAR;
    READ_A(1)
    MFMA_Q(1, 1)
    // P4 (1,0): B0 already resident -> no vmcnt
    STAGE_A(1) BAR;
    READ_B(0)
    MFMA_Q(1, 0)
  }

  // ---- fused epilogue via LDS transpose (coalesced 128B row stores) ----
  // First __syncthreads drains vmcnt(0)+lgkmcnt(0): phantom tile-8 stages land
  // in buf0 before we overwrite lds with the chunk buffer.
  float g_[4], wq_[4];
#pragma unroll
  for (int ni = 0; ni < 4; ++ni) {
    int col = n0 + wn * 64 + ni * 16 + lr;
    g_[ni]  = (col < K_OUT) ? gamma[col] : 0.f;
    wq_[ni] = (col < K_OUT) ? wsq[col]   : 0.f;
  }
  float* ch = (float*)lds;       // chunk buffer [64][260] f32 (pad 260: 16B-aligned
  const int rl = tid >> 3;       // rows, 2-way-max LDS bank aliasing)
  const int cb = (tid & 7) << 2;
#pragma unroll
  for (int c = 0; c < 4; ++c) {
    __syncthreads();   // previous chunk fully read (and K-loop LDS quiesced)
    if (wm == (c >> 1)) {
#pragma unroll
      for (int mi2 = 0; mi2 < 4; ++mi2) {
        const int mi    = ((c & 1) << 2) + mi2;
        const int row_l = mi2 * 16 + lk4 * 4;
        const int grow  = m0 + c * 64 + row_l;
#pragma unroll
        for (int j = 0; j < 4; ++j) {
          float dq = dsq[grow + j];
#pragma unroll
          for (int ni = 0; ni < 4; ++ni) {
            ch[(row_l + j) * 260 + wn * 64 + ni * 16 + lr] =
                g_[ni] * (2.f * acc[mi][ni][j] - dq - wq_[ni]);
          }
        }
      }
    }
    __syncthreads();   // chunk visible to all waves
#pragma unroll
    for (int s = 0; s < 8; ++s) {
      int col = cb + s * 32;
      if (n0 + col < K_OUT) {
        float4 v = *(const float4*)&ch[rl * 260 + col];
        *(float4*)&out[(size_t)(m0 + c * 64 + rl) * K_OUT + n0 + col] = v;
      }
    }
  }
}

extern "C" void kernel_launch(void* const* d_in, const int* in_sizes, int n_in,
                              void* d_out, int out_size, void* d_ws, size_t ws_size,
                              hipStream_t stream) {
  const float* D     = (const float*)d_in[0];
  const float* W     = (const float*)d_in[1];
  const float* gamma = (const float*)d_in[2];
  float* out = (float*)d_out;
  char*  ws  = (char*)d_ws;

  u16*   Db  = (u16*)(ws + OFF_DB);
  u16*   Wb  = (u16*)(ws + OFF_WB);
  float* dsq = (float*)(ws + OFF_DSQ);
  float* wsq = (float*)(ws + OFF_WSQ);

  prep<<<B_ROWS / 4 + K_PAD / 4, 256, 0, stream>>>(D, W, Db, Wb, dsq, wsq);

  // grid = (16384/256) * (1024/256) = 64*4 = 256 blocks, 1 per CU
  gemm_eps<<<(B_ROWS / BM) * (K_PAD / BN), 512, 0, stream>>>(
      Db, Wb, dsq, wsq, gamma, out);
}

// Round 4
// 40.477 us; speedup vs baseline: 1.1730x; 1.0428x over previous
//
#include <hip/hip_runtime.h>
#include <hip/hip_bf16.h>
#include <stdint.h>

// Problem constants
#define B_ROWS 16384
#define F_DIM  512
#define K_OUT  1000
#define K_PAD  1024

// GEMM tile (128x128, BK=64, 4 waves, 64KB LDS -> 2 blocks/CU resident)
#define BM 128
#define BN 128
#define BK 64

typedef __attribute__((ext_vector_type(4))) float f32x4;
typedef __attribute__((ext_vector_type(8))) short short8;
typedef unsigned short u16;
typedef unsigned int   u32;

// Workspace layout (bytes)
#define OFF_DB   0                               // 16384*512*2 = 16777216
#define OFF_WB   16777216                        // 1024*512*2  = 1048576
#define OFF_DSQ  (16777216 + 1048576)            // 16384*4     = 65536
#define OFF_WSQ  (16777216 + 1048576 + 65536)    // 1024*4      = 4096

__device__ __forceinline__ u16 f2bf(float f) {
  union { float f; u32 u; } v; v.f = f;
  u32 u = v.u;
  u32 r = (u + 0x7fffu + ((u >> 16) & 1u)) >> 16;   // RNE
  return (u16)r;
}

// ---- merged prep: cast D,W -> bf16 (+pad W), row sums of squares ----
__global__ void prep(const float* __restrict__ D, const float* __restrict__ W,
                     u16* __restrict__ Db, u16* __restrict__ Wb,
                     float* __restrict__ dsq, float* __restrict__ wsq) {
  int w    = threadIdx.x >> 6;
  int lane = threadIdx.x & 63;
  if (blockIdx.x < B_ROWS / 4) {
    int row = blockIdx.x * 4 + w;
    const float* src = D + (size_t)row * F_DIM + lane * 8;
    float4 v0 = *(const float4*)src;
    float4 v1 = *(const float4*)(src + 4);
    float s = v0.x*v0.x + v0.y*v0.y + v0.z*v0.z + v0.w*v0.w
            + v1.x*v1.x + v1.y*v1.y + v1.z*v1.z + v1.w*v1.w;
#pragma unroll
    for (int off = 32; off >= 1; off >>= 1) s += __shfl_xor(s, off);
    if (lane == 0) dsq[row] = s;
    uint4 p;
    p.x = (u32)f2bf(v0.x) | ((u32)f2bf(v0.y) << 16);
    p.y = (u32)f2bf(v0.z) | ((u32)f2bf(v0.w) << 16);
    p.z = (u32)f2bf(v1.x) | ((u32)f2bf(v1.y) << 16);
    p.w = (u32)f2bf(v1.z) | ((u32)f2bf(v1.w) << 16);
    *(uint4*)(Db + (size_t)row * F_DIM + lane * 8) = p;
  } else {
    int row = (blockIdx.x - B_ROWS / 4) * 4 + w;
    uint4 p; p.x = p.y = p.z = p.w = 0u;
    float s = 0.f;
    if (row < K_OUT) {
      const float* src = W + (size_t)row * F_DIM + lane * 8;
      float4 v0 = *(const float4*)src;
      float4 v1 = *(const float4*)(src + 4);
      s = v0.x*v0.x + v0.y*v0.y + v0.z*v0.z + v0.w*v0.w
        + v1.x*v1.x + v1.y*v1.y + v1.z*v1.z + v1.w*v1.w;
      p.x = (u32)f2bf(v0.x) | ((u32)f2bf(v0.y) << 16);
      p.y = (u32)f2bf(v0.z) | ((u32)f2bf(v0.w) << 16);
      p.z = (u32)f2bf(v1.x) | ((u32)f2bf(v1.y) << 16);
      p.w = (u32)f2bf(v1.z) | ((u32)f2bf(v1.w) << 16);
    }
#pragma unroll
    for (int off = 32; off >= 1; off >>= 1) s += __shfl_xor(s, off);
    if (lane == 0) wsq[row] = s;
    *(uint4*)(Wb + (size_t)row * F_DIM + lane * 8) = p;
  }
}

// ---- async global -> LDS, 16B per lane (dest is wave-uniform base + lane*16) ----
__device__ __forceinline__ void gload_lds16(const void* g, void* l) {
  __builtin_amdgcn_global_load_lds(
      (const __attribute__((address_space(1))) void*)g,
      (__attribute__((address_space(3))) void*)l,
      16, 0, 0);
}

// ---- main GEMM + fused epilogue: 128x128 tile, 4 waves, counted-vmcnt pipeline ----
// out[m][n] = gamma[n] * (2*cross[m][n] - dsq[m] - wsq[n]), n < K_OUT
//
// LDS tile: [128 rows][64 cols] bf16 (16KB each for A,B; double-buffered = 64KB
// total -> 2 blocks/CU so one block's epilogue/staging overlaps the other's MFMA).
// Row = 128B = 8 slots of 16B; slot stored at (slot ^ (row&7)) via pre-swizzled
// global source (both-sides involution, rule #21). Reads use the same XOR.
//
// Chunks (Gray-code phases (0,0)(0,1)(1,1)(1,0)):
//   A_h = A rows {h*32+0..31, h*32+64..95}   (what READ_A(h) touches across wm=0/1)
//   B_q = B rows {q*32+0..31, q*32+64..95}   (what READ_B(q) touches across wn=0/1)
// Per-thread ledger (2 loads per chunk, issue order A0,B0,B1,A1 per tile):
//   enter tile: 8 outstanding; P1 +2 -> vmcnt(6) completes A0,B0; P2 +2 ->
//   vmcnt(6) completes B1; P3 +2 -> vmcnt(6) completes A1; P4 +2, no wait.
//   Never below 6 in flight; no vmcnt(0) anywhere in the main loop (T4).

#define READ_A(QM)                                                             \
  _Pragma("unroll") for (int mi2 = 0; mi2 < 2; ++mi2)                          \
  _Pragma("unroll") for (int kk = 0; kk < 2; ++kk) {                           \
    int r = wm * 64 + (QM) * 32 + mi2 * 16 + lr;                               \
    a[mi2][kk] = *(const short8*)(sAc + r * 128 +                              \
                                  ((((kk << 2) + lk4) ^ (r & 7)) << 4));       \
  }

#define READ_B(QN)                                                             \
  _Pragma("unroll") for (int ni2 = 0; ni2 < 2; ++ni2)                          \
  _Pragma("unroll") for (int kk = 0; kk < 2; ++kk) {                           \
    int r = wn * 64 + (QN) * 32 + ni2 * 16 + lr;                               \
    b[ni2][kk] = *(const short8*)(sBc + r * 128 +                              \
                                  ((((kk << 2) + lk4) ^ (r & 7)) << 4));       \
  }

// Stage chunk A_h of the next K-tile: rows h*32 + {0..31} and h*32+64 + {0..31}.
#define STAGE_A(h)                                                             \
  _Pragma("unroll") for (int j = 0; j < 2; ++j) {                              \
    int rb = (h) * 32 + j * 64 + w * 8;                                        \
    int r  = rb + (lane >> 3);                                                 \
    int sc = s8 ^ (r & 7);                                                     \
    gload_lds16(Ag + (size_t)r * F_DIM + kbn + sc * 8, sAn + rb * 128);        \
  }

#define STAGE_B(q)                                                             \
  _Pragma("unroll") for (int j = 0; j < 2; ++j) {                              \
    int rb = (q) * 32 + j * 64 + w * 8;                                        \
    int r  = rb + (lane >> 3);                                                 \
    int sc = s8 ^ (r & 7);                                                     \
    gload_lds16(Bg + (size_t)r * F_DIM + kbn + sc * 8, sBn + rb * 128);        \
  }

#define MFMA_Q(QM, QN)                                                         \
  asm volatile("s_waitcnt lgkmcnt(0)" ::: "memory");                           \
  __builtin_amdgcn_sched_barrier(0);                                           \
  __builtin_amdgcn_s_setprio(1);                                               \
  _Pragma("unroll") for (int mi2 = 0; mi2 < 2; ++mi2)                          \
  _Pragma("unroll") for (int ni2 = 0; ni2 < 2; ++ni2)                          \
  _Pragma("unroll") for (int kk = 0; kk < 2; ++kk)                             \
    acc[(QM)*2 + mi2][(QN)*2 + ni2] =                                          \
        __builtin_amdgcn_mfma_f32_16x16x32_bf16(                               \
            a[mi2][kk], b[ni2][kk], acc[(QM)*2 + mi2][(QN)*2 + ni2], 0, 0, 0); \
  __builtin_amdgcn_s_setprio(0);                                               \
  __builtin_amdgcn_s_barrier();

#define VM6  asm volatile("s_waitcnt vmcnt(6)" ::: "memory")
#define BAR  __builtin_amdgcn_s_barrier()

__global__ __launch_bounds__(256, 2) void gemm_eps(
    const u16* __restrict__ A,   // [B_ROWS][F_DIM] bf16
    const u16* __restrict__ Bw,  // [K_PAD][F_DIM]  bf16 (padded rows are 0)
    const float* __restrict__ dsq,
    const float* __restrict__ wsq,
    const float* __restrict__ gamma,
    float* __restrict__ out) {
  __shared__ __align__(16) char lds[65536];   // 2 x (A 16KB + B 16KB)

  const int tid  = threadIdx.x;
  const int w    = tid >> 6;     // wave 0..3
  const int lane = tid & 63;
  const int lr   = lane & 15;
  const int lk4  = lane >> 4;
  const int wm   = w >> 1;       // 2 M-waves
  const int wn   = w & 1;        // 2 N-waves

  // XCD-aware swizzle (grid=1024, %8==0 -> bijective). Consecutive wg on one
  // XCD share the A-panel (same mt) -> A re-reads are local-L2 hits.
  const int bid = blockIdx.x;
  const int wg  = (bid & 7) * 128 + (bid >> 3);
  const int mt  = wg >> 3;       // 128 M-tiles
  const int nt  = wg & 7;        // 8 N-tiles
  const int m0  = mt * BM;
  const int n0  = nt * BN;

  const u16* Ag = A  + (size_t)m0 * F_DIM;
  const u16* Bg = Bw + (size_t)n0 * F_DIM;

  const int s8 = lane & 7;       // staging 16B slot

  f32x4 acc[4][4];
#pragma unroll
  for (int i = 0; i < 4; ++i)
#pragma unroll
    for (int j = 0; j < 4; ++j) acc[i][j] = (f32x4){0.f, 0.f, 0.f, 0.f};

  // prologue: stage all 4 chunks of K-tile 0 into buf0, in ledger order.
  {
    char* sAn = lds;
    char* sBn = lds + 16384;
    const int kbn = 0;
    STAGE_A(0) STAGE_B(0) STAGE_B(1) STAGE_A(1)
  }
  // no wait here: P1 of tile 0 does vmcnt(6) which completes A0,B0.

#pragma unroll 2
  for (int t = 0; t < 8; ++t) {
    char* sAc = lds + (t & 1) * 32768;
    char* sBc = sAc + 16384;
    char* sAn = lds + ((t + 1) & 1) * 32768;
    char* sBn = sAn + 16384;
    const int kbn = ((t + 1) & 7) * BK;  // tile 8 wraps to k=0: harmless, drained later
    short8 a[2][2], b[2][2];

    // P1 (QM=0,QN=0): needs A0,B0 of this tile
    STAGE_A(0) VM6; BAR;
    READ_A(0) READ_B(0)
    MFMA_Q(0, 0)
    // P2 (0,1): needs B1
    STAGE_B(0) VM6; BAR;
    READ_B(1)
    MFMA_Q(0, 1)
    // P3 (1,1): needs A1
    STAGE_B(1) VM6; BAR;
    READ_A(1)
    MFMA_Q(1, 1)
    // P4 (1,0): B0 already resident -> no vmcnt
    STAGE_A(1) BAR;
    READ_B(0)
    MFMA_Q(1, 0)
  }

  // ---- fused epilogue via LDS transpose (coalesced 128B row stores) ----
  // First __syncthreads drains vmcnt(0)+lgkmcnt(0): phantom tile-8 stages land
  // in buf0 before we overwrite lds with the chunk buffer.
  float g_[4], wq_[4];
#pragma unroll
  for (int ni = 0; ni < 4; ++ni) {
    int col = n0 + wn * 64 + ni * 16 + lr;
    g_[ni]  = (col < K_OUT) ? gamma[col] : 0.f;
    wq_[ni] = (col < K_OUT) ? wsq[col]   : 0.f;
  }
  float* ch = (float*)lds;       // chunk buffer [64][132] f32 (pad 132 -> <=2-way
  const int rl = tid >> 3;       // bank aliasing on write, 16B-aligned rows)
  const int cb = (tid & 7) << 2;
#pragma unroll
  for (int c = 0; c < 2; ++c) {
    __syncthreads();   // previous chunk fully read (and K-loop LDS quiesced)
    if (wm == c) {
#pragma unroll
      for (int mi = 0; mi < 4; ++mi) {
        const int row_l = mi * 16 + lk4 * 4;
        const int grow  = m0 + c * 64 + row_l;
#pragma unroll
        for (int j = 0; j < 4; ++j) {
          float dq = dsq[grow + j];
#pragma unroll
          for (int ni = 0; ni < 4; ++ni) {
            ch[(row_l + j) * 132 + wn * 64 + ni * 16 + lr] =
                g_[ni] * (2.f * acc[mi][ni][j] - dq - wq_[ni]);
          }
        }
      }
    }
    __syncthreads();   // chunk visible to all waves
#pragma unroll
    for (int half = 0; half < 2; ++half) {
#pragma unroll
      for (int s = 0; s < 4; ++s) {
        int row = half * 32 + rl;
        int col = cb + s * 32;
        if (n0 + col < K_OUT) {
          float4 v = *(const float4*)&ch[row * 132 + col];
          *(float4*)&out[(size_t)(m0 + c * 64 + row) * K_OUT + n0 + col] = v;
        }
      }
    }
  }
}

extern "C" void kernel_launch(void* const* d_in, const int* in_sizes, int n_in,
                              void* d_out, int out_size, void* d_ws, size_t ws_size,
                              hipStream_t stream) {
  const float* D     = (const float*)d_in[0];
  const float* W     = (const float*)d_in[1];
  const float* gamma = (const float*)d_in[2];
  float* out = (float*)d_out;
  char*  ws  = (char*)d_ws;

  u16*   Db  = (u16*)(ws + OFF_DB);
  u16*   Wb  = (u16*)(ws + OFF_WB);
  float* dsq = (float*)(ws + OFF_DSQ);
  float* wsq = (float*)(ws + OFF_WSQ);

  prep<<<B_ROWS / 4 + K_PAD / 4, 256, 0, stream>>>(D, W, Db, Wb, dsq, wsq);

  // grid = (16384/128) * (1024/128) = 128*8 = 1024 blocks, 2 resident/CU
  gemm_eps<<<(B_ROWS / BM) * (K_PAD / BN), 256, 0, stream>>>(
      Db, Wb, dsq, wsq, gamma, out);
}